// Round 1
// baseline (111.512 us; speedup 1.0000x reference)
//
#include <hip/hip_runtime.h>

// TransE scoring: two 64x40000 L1-distance matrices vs lhs_weight + 3 gathers.
// D[q][e] = sum_r |C[q][r] - W[e][r]|, C rows 0..63 = lhs+rel, 64..127 = rhs-rel.
// out layout: [-sp (64*40000)] [-po (64*40000)] [lhs 64*256] [rel 64*256] [rhs 64*256]

#define NENT 40000
#define RANK 256
#define NB   64          // batch
#define M    128         // 2*NB query rows
#define BN   64          // entities per block  (40000 = 625 * 64)
#define KC   64          // K chunk staged in LDS
#define NCHUNK (RANK/KC) // 4

__global__ __launch_bounds__(64) void prep_kernel(
    const int*   __restrict__ x,
    const float* __restrict__ lhsW,
    const float* __restrict__ relW,
    float*       __restrict__ out,
    float*       __restrict__ C)
{
    const int b = blockIdx.x;   // 0..63
    const int t = threadIdx.x;  // 0..63, 4 floats each
    const int i0 = x[b*3+0];
    const int i1 = x[b*3+1];
    const int i2 = x[b*3+2];
    const float4 l = *(const float4*)(lhsW + i0*RANK + t*4);
    const float4 r = *(const float4*)(relW + i1*RANK + t*4);
    const float4 h = *(const float4*)(lhsW + i2*RANK + t*4);
    float* tail = out + 2*NB*NENT;
    *(float4*)(tail +                b*RANK + t*4) = l;
    *(float4*)(tail +   NB*RANK +    b*RANK + t*4) = r;
    *(float4*)(tail + 2*NB*RANK +    b*RANK + t*4) = h;
    const float4 q = make_float4(l.x+r.x, l.y+r.y, l.z+r.z, l.w+r.w);
    const float4 p = make_float4(h.x-r.x, h.y-r.y, h.z-r.z, h.w-r.w);
    *(float4*)(C +      b *RANK + t*4) = q;
    *(float4*)(C + (NB+b)*RANK + t*4) = p;
}

// LDS layout: row-major [rows][KC] but 16B slots within a row are XOR-swizzled:
// LDS slot sl of row r holds global k4-slot (sl ^ (r&15)). Staging writes and
// fragment reads both apply the same swizzle -> minimum bank aliasing on both.
__global__ __launch_bounds__(256) void score_kernel(
    const float* __restrict__ W,    // lhs_weight [40000][256]
    const float* __restrict__ C,    // [128][256] queries (from ws)
    float*       __restrict__ out)  // [128][40000]
{
    __shared__ alignas(16) float ldsC[M*KC];   // 32 KB
    __shared__ alignas(16) float ldsW[BN*KC];  // 16 KB
    const int tid = threadIdx.x;
    const int tx  = tid & 15;   // entity dir: n = tx + 16j, j=0..3
    const int ty  = tid >> 4;   // query  dir: m = ty + 16i, i=0..7
    const int e0  = blockIdx.x * BN;

    float acc[8][4];
    #pragma unroll
    for (int i = 0; i < 8; ++i)
        #pragma unroll
        for (int j = 0; j < 4; ++j) acc[i][j] = 0.f;

    for (int c = 0; c < NCHUNK; ++c) {
        const int kc = c * KC;
        if (c) __syncthreads();   // uniform branch; protect LDS reuse
        // stage C chunk: 128 rows x 16 slots = 2048 slots, 8 per thread
        #pragma unroll
        for (int q = 0; q < 8; ++q) {
            const int sf = tid + q*256;
            const int rr = sf >> 4;
            const int s  = sf & 15;
            const float4 v = *(const float4*)(C + rr*RANK + kc + s*4);
            *(float4*)(ldsC + rr*KC + ((s ^ (rr & 15)) << 2)) = v;
        }
        // stage W chunk: 64 rows x 16 slots = 1024 slots, 4 per thread
        #pragma unroll
        for (int q = 0; q < 4; ++q) {
            const int sf = tid + q*256;
            const int rr = sf >> 4;
            const int s  = sf & 15;
            const float4 v = *(const float4*)(W + (e0 + rr)*RANK + kc + s*4);
            *(float4*)(ldsW + rr*KC + ((s ^ (rr & 15)) << 2)) = v;
        }
        __syncthreads();

        #pragma unroll 4
        for (int k4 = 0; k4 < KC/4; ++k4) {
            float4 cf[8], wf[4];
            #pragma unroll
            for (int i = 0; i < 8; ++i)   // row&15 == ty -> swizzled slot k4^ty
                cf[i] = *(const float4*)(ldsC + (ty + 16*i)*KC + ((k4 ^ ty) << 2));
            #pragma unroll
            for (int j = 0; j < 4; ++j)   // row&15 == tx -> swizzled slot k4^tx
                wf[j] = *(const float4*)(ldsW + (tx + 16*j)*KC + ((k4 ^ tx) << 2));
            #pragma unroll
            for (int i = 0; i < 8; ++i)
                #pragma unroll
                for (int j = 0; j < 4; ++j) {
                    acc[i][j] += fabsf(cf[i].x - wf[j].x)
                               + fabsf(cf[i].y - wf[j].y)
                               + fabsf(cf[i].z - wf[j].z)
                               + fabsf(cf[i].w - wf[j].w);
                }
        }
    }

    #pragma unroll
    for (int i = 0; i < 8; ++i) {
        const int m = ty + 16*i;
        #pragma unroll
        for (int j = 0; j < 4; ++j)
            out[m*NENT + e0 + tx + 16*j] = -acc[i][j];
    }
}

extern "C" void kernel_launch(void* const* d_in, const int* in_sizes, int n_in,
                              void* d_out, int out_size, void* d_ws, size_t ws_size,
                              hipStream_t stream) {
    const int*   x    = (const int*)d_in[0];    // (64,3) indices
    const float* lhsW = (const float*)d_in[1];  // (40000,256)
    const float* relW = (const float*)d_in[2];  // (40000,256)
    float* out = (float*)d_out;
    float* C   = (float*)d_ws;                  // 128*256 floats = 128 KB

    prep_kernel<<<NB, 64, 0, stream>>>(x, lhsW, relW, out, C);
    score_kernel<<<NENT/BN, 256, 0, stream>>>(lhsW, C, out);
}